// Round 1
// baseline (276.868 us; speedup 1.0000x reference)
//
#include <hip/hip_runtime.h>

// RepulsionLoss: points [B=4, N=8192, 3] fp32 -> scalar = ALPHA * mean over
// [B,N,K=8] of (RADIUS - dn) * exp(-dn^2/H^2), dn = dist to k-th nearest
// neighbor (incl. self). Only the 8 smallest distances per point matter —
// no index gather needed.
//
// Round 1: brute-force N^2 scan, LDS-tiled, 4-way j-split per point,
// branchless sorted-8 insert gated by wave-uniform __any (no divergence).

#define B_    4
#define N_    8192
#define KNN_  8
#define TILE_ 2048   // points per LDS tile (24 KB)

constexpr float RADIUS_  = 0.07f;
constexpr float INV_H2_  = 1.0f / (0.03f * 0.03f);
constexpr float SCALE_   = 0.1f / (float)(B_ * N_ * KNN_);  // ALPHA / (B*N*K)

__global__ void zero_kernel(float* out) { out[0] = 0.0f; }

__global__ __launch_bounds__(256) void repulsion_kernel(
        const float* __restrict__ pts, float* __restrict__ out) {
    __shared__ float tile[TILE_ * 3];     // 24 KB
    __shared__ float mergebuf[64 * 32];   // 8 KB: 64 points x (4 splits x 8)
    __shared__ float lds_sum;

    const int tid = threadIdx.x;
    const int p   = tid >> 2;             // 0..63: point within block
    const int s   = tid & 3;              // 0..3 : j-range split
    const int blk = blockIdx.x;           // 0..511
    const int b   = blk >> 7;             // batch (128 blocks per batch)
    const int i   = ((blk & 127) << 6) + p;

    if (tid == 0) lds_sum = 0.0f;

    const float* base = pts + (size_t)b * N_ * 3;
    const float px = base[i * 3 + 0];
    const float py = base[i * 3 + 1];
    const float pz = base[i * 3 + 2];

    // sorted ascending; t[7] = current 8th-smallest d^2
    float t[KNN_];
#pragma unroll
    for (int k = 0; k < KNN_; k++) t[k] = 1e30f;

    for (int tb = 0; tb < N_ / TILE_; tb++) {
        // cooperative tile load: TILE_*3 = 6144 floats = 1536 float4
        const float4* gsrc = (const float4*)(base + tb * (TILE_ * 3));
        float4*       ldst = (float4*)tile;
#pragma unroll
        for (int q = 0; q < (TILE_ * 3 / 4) / 256; q++)
            ldst[tid + q * 256] = gsrc[tid + q * 256];
        __syncthreads();

        for (int m = 0; m < TILE_ / 4; m++) {
            const int jl = (m << 2) + s;
            const float qx = tile[jl * 3 + 0];
            const float qy = tile[jl * 3 + 1];
            const float qz = tile[jl * 3 + 2];
            const float dx = px - qx, dy = py - qy, dz = pz - qz;
            const float d2 = dx * dx + dy * dy + dz * dz;
            // wave-uniform gate: if no lane improves, skip insert entirely.
            // Inserting a non-qualifying d2 is harmless (falls off the end),
            // so all lanes run the branchless insert together: no divergence.
            if (__any(d2 < t[KNN_ - 1])) {
                float x = d2;
#pragma unroll
                for (int k = 0; k < KNN_; k++) {
                    const float lo = fminf(t[k], x);
                    x = fmaxf(t[k], x);
                    t[k] = lo;
                }
            }
        }
        __syncthreads();
    }

    // merge the 4 per-split sorted-8 lists for each point
#pragma unroll
    for (int k = 0; k < KNN_; k++) mergebuf[p * 32 + s * 8 + k] = t[k];
    __syncthreads();

    if (s == 0) {
        for (int v = 8; v < 32; v++) {
            float x = mergebuf[p * 32 + v];
#pragma unroll
            for (int k = 0; k < KNN_; k++) {
                const float lo = fminf(t[k], x);
                x = fmaxf(t[k], x);
                t[k] = lo;
            }
        }
        float sum = 0.0f;
#pragma unroll
        for (int k = 0; k < KNN_; k++) {
            const float dm = fmaxf(t[k], 1e-12f);  // self: d2=0 -> dn=1e-6
            const float dn = sqrtf(dm);
            const float w  = __expf(-dm * INV_H2_);
            sum += (RADIUS_ - dn) * w;
        }
        atomicAdd(&lds_sum, sum);
    }
    __syncthreads();
    if (tid == 0) atomicAdd(out, lds_sum * SCALE_);
}

extern "C" void kernel_launch(void* const* d_in, const int* in_sizes, int n_in,
                              void* d_out, int out_size, void* d_ws, size_t ws_size,
                              hipStream_t stream) {
    const float* pts = (const float*)d_in[0];
    float*       out = (float*)d_out;

    zero_kernel<<<1, 1, 0, stream>>>(out);
    repulsion_kernel<<<B_ * N_ / 64, 256, 0, stream>>>(pts, out);
}

// Round 2
// 252.798 us; speedup vs baseline: 1.0952x; 1.0952x over previous
//
#include <hip/hip_runtime.h>

// RepulsionLoss: points [B=4, N=8192, 3] fp32 -> scalar.
// Only the 8 smallest distances per point matter.
//
// Round 2: uniform-grid exact kNN. Cell-sort the points (count/scan/scatter),
// then per-point ring expansion with early termination:
//   after ring r is done, any unseen point is >= r*g away, so stop when
//   t[7] <= ((r-1)*g)^2 before starting ring r.
// 4-way split of ring cells per point (as in R1) for occupancy; per-split
// early break is safe: split s stops only when it already holds 8 distinct
// distances <= the bound, so skipped cells cannot enter the global top-8.

#define B_    4
#define N_    8192
#define KNN_  8
#define G_    12
#define C_    (G_ * G_ * G_)   // 1728 cells
#define CS_   (C_ + 1)         // 1729 cellStart entries

constexpr float GF_     = (float)G_;
constexpr float CELL_   = 1.0f / GF_;
constexpr float RADIUS_ = 0.07f;
constexpr float INV_H2_ = 1.0f / (0.03f * 0.03f);
constexpr float SCALE_  = 0.1f / (float)(B_ * N_ * KNN_);   // ALPHA / (B*N*K)

__device__ __forceinline__ int cell_coord(float x) {
    int c = (int)(x * GF_);
    return min(max(c, 0), G_ - 1);
}

__global__ __launch_bounds__(256) void count_kernel(const float* __restrict__ pts,
                                                    int* __restrict__ counts) {
    const int g = blockIdx.x * 256 + threadIdx.x;   // 0..B*N-1
    const int b = g >> 13;
    const float x = pts[g * 3 + 0], y = pts[g * 3 + 1], z = pts[g * 3 + 2];
    const int id = (cell_coord(z) * G_ + cell_coord(y)) * G_ + cell_coord(x);
    atomicAdd(&counts[b * C_ + id], 1);
}

__global__ __launch_bounds__(256) void scan_kernel(const int* __restrict__ counts,
                                                   int* __restrict__ cellStart,
                                                   int* __restrict__ cursor) {
    __shared__ int lsum[256];
    const int b = blockIdx.x, t = threadIdx.x;
    const int* cnt = counts + b * C_;
    int vals[7], tot = 0;
    const int c0 = t * 7;                            // 256*7 = 1792 >= 1728
#pragma unroll
    for (int k = 0; k < 7; k++) {
        const int c = c0 + k;
        const int v = (c < C_) ? cnt[c] : 0;
        vals[k] = v; tot += v;
    }
    lsum[t] = tot;
    __syncthreads();
    for (int off = 1; off < 256; off <<= 1) {        // inclusive Hillis-Steele
        const int v = (t >= off) ? lsum[t - off] : 0;
        __syncthreads();
        lsum[t] += v;
        __syncthreads();
    }
    int run = lsum[t] - tot;                         // exclusive base
#pragma unroll
    for (int k = 0; k < 7; k++) {
        const int c = c0 + k;
        if (c < C_) {
            cellStart[b * CS_ + c] = run;
            cursor[b * C_ + c]     = run;
            run += vals[k];
        }
    }
    if (t == 255) cellStart[b * CS_ + C_] = N_;
}

__global__ __launch_bounds__(256) void scatter_kernel(const float* __restrict__ pts,
                                                      int* __restrict__ cursor,
                                                      float4* __restrict__ sorted4) {
    const int g = blockIdx.x * 256 + threadIdx.x;
    const int b = g >> 13;
    const float x = pts[g * 3 + 0], y = pts[g * 3 + 1], z = pts[g * 3 + 2];
    const int id = (cell_coord(z) * G_ + cell_coord(y)) * G_ + cell_coord(x);
    const int pos = atomicAdd(&cursor[b * C_ + id], 1);
    sorted4[b * N_ + pos] = make_float4(x, y, z, 0.0f);
}

__global__ __launch_bounds__(256) void query_kernel(const float4* __restrict__ sorted4,
                                                    const int* __restrict__ cellStart,
                                                    float* __restrict__ out) {
    __shared__ int   cs[CS_];                // 6.9 KB: this batch's cellStart
    __shared__ float mergebuf[64 * 32];      // 8 KB
    __shared__ float lds_sum;

    const int tid = threadIdx.x;
    const int p   = tid >> 2;                // 0..63 point-in-block
    const int s   = tid & 3;                 // 0..3  ring-cell split
    const int blk = blockIdx.x;              // 0..511
    const int b   = blk >> 7;
    const int i   = ((blk & 127) << 6) + p;  // sorted index within batch

    for (int q = 0; q < 7; q++) {
        const int idx = tid + q * 256;
        if (idx < CS_) cs[idx] = cellStart[b * CS_ + idx];
    }
    if (tid == 0) lds_sum = 0.0f;
    __syncthreads();

    const float4* sp = sorted4 + b * N_;
    const float4 P = sp[i];
    const int cx = cell_coord(P.x), cy = cell_coord(P.y), cz = cell_coord(P.z);

    float t[KNN_];
#pragma unroll
    for (int k = 0; k < KNN_; k++) t[k] = 1e30f;

    for (int r = 0; r < G_; r++) {
        if (r >= 1) {
            const float dmin = (float)(r - 1) * CELL_;
            if (t[KNN_ - 1] <= dmin * dmin) break;   // exact-kNN stop
        }
        int ctr = 0;
        for (int dz = -r; dz <= r; ++dz)
        for (int dy = -r; dy <= r; ++dy)
        for (int dx = -r; dx <= r; ++dx) {
            const int ch = max(abs(dz), max(abs(dy), abs(dx)));
            if (ch != r) continue;                   // shell only
            const int my = ctr++;
            if ((my & 3) != s) continue;             // 4-way split
            const int z = cz + dz, y = cy + dy, x = cx + dx;
            if ((unsigned)z >= G_ || (unsigned)y >= G_ || (unsigned)x >= G_) continue;
            const int id = (z * G_ + y) * G_ + x;
            const int j0 = cs[id], j1 = cs[id + 1];
            for (int j = j0; j < j1; ++j) {
                const float4 Q = sp[j];
                const float ddx = P.x - Q.x, ddy = P.y - Q.y, ddz = P.z - Q.z;
                const float d2 = ddx * ddx + ddy * ddy + ddz * ddz;
                if (d2 < t[KNN_ - 1]) {
                    float v = d2;
#pragma unroll
                    for (int k = 0; k < KNN_; k++) {
                        const float lo = fminf(t[k], v);
                        v = fmaxf(t[k], v);
                        t[k] = lo;
                    }
                }
            }
        }
    }

    // merge the 4 per-split sorted-8 lists for each point
#pragma unroll
    for (int k = 0; k < KNN_; k++) mergebuf[p * 32 + s * 8 + k] = t[k];
    __syncthreads();

    if (s == 0) {
        for (int v2 = 8; v2 < 32; ++v2) {
            float x = mergebuf[p * 32 + v2];
#pragma unroll
            for (int k = 0; k < KNN_; k++) {
                const float lo = fminf(t[k], x);
                x = fmaxf(t[k], x);
                t[k] = lo;
            }
        }
        float sum = 0.0f;
#pragma unroll
        for (int k = 0; k < KNN_; k++) {
            const float dm = fmaxf(t[k], 1e-12f);    // self: d2=0 -> dn=1e-6
            const float dn = sqrtf(dm);
            sum += (RADIUS_ - dn) * __expf(-dm * INV_H2_);
        }
        atomicAdd(&lds_sum, sum);
    }
    __syncthreads();
    if (tid == 0) atomicAdd(out, lds_sum * SCALE_);
}

extern "C" void kernel_launch(void* const* d_in, const int* in_sizes, int n_in,
                              void* d_out, int out_size, void* d_ws, size_t ws_size,
                              hipStream_t stream) {
    const float* pts = (const float*)d_in[0];
    float*       out = (float*)d_out;

    // workspace layout (bytes)
    char* ws = (char*)d_ws;
    float4* sorted4   = (float4*)(ws);                        // B*N*16   = 524288
    int*    counts    = (int*)(ws + 524288);                  // B*C*4    =  27648
    int*    cellStart = (int*)(ws + 524288 + 27648);          // B*CS*4   =  27664
    int*    cursor    = (int*)(ws + 524288 + 27648 + 27664);  // B*C*4    =  27648

    hipMemsetAsync(counts, 0, B_ * C_ * sizeof(int), stream);
    hipMemsetAsync(out, 0, sizeof(float), stream);

    count_kernel  <<<B_ * N_ / 256, 256, 0, stream>>>(pts, counts);
    scan_kernel   <<<B_,            256, 0, stream>>>(counts, cellStart, cursor);
    scatter_kernel<<<B_ * N_ / 256, 256, 0, stream>>>(pts, cursor, sorted4);
    query_kernel  <<<B_ * N_ / 64,  256, 0, stream>>>(sorted4, cellStart, out);
}

// Round 3
// 127.147 us; speedup vs baseline: 2.1775x; 1.9882x over previous
//
#include <hip/hip_runtime.h>

// RepulsionLoss: points [B=4, N=8192, 3] fp32 -> scalar.
// Round 3: grid kNN with j-interleaved splits (no exec-masked cell split),
// merged-bound exact ring-2+ fallback for boundary/sparse points, and a
// single fused build kernel (count+scan+scatter+zero-out). 2 dispatches.

#define B_    4
#define N_    8192
#define KNN_  8
#define G_    12
#define C_    (G_ * G_ * G_)   // 1728
#define CS_   (C_ + 1)
#define PPT_  (N_ / 256)       // 32 points per thread in build

constexpr float GF_     = (float)G_;
constexpr float CELL_   = 1.0f / GF_;
constexpr float RADIUS_ = 0.07f;
constexpr float INV_H2_ = 1.0f / (0.03f * 0.03f);
constexpr float SCALE_  = 0.1f / (float)(B_ * N_ * KNN_);   // ALPHA / (B*N*K)

__device__ __forceinline__ int cell_coord(float x) {
    int c = (int)(x * GF_);
    return min(max(c, 0), G_ - 1);
}

__device__ __forceinline__ void insert8(float (&t)[KNN_], float v) {
#pragma unroll
    for (int k = 0; k < KNN_; k++) {
        const float lo = fminf(t[k], v);
        v = fmaxf(t[k], v);
        t[k] = lo;
    }
}

// One block per batch: LDS count -> LDS scan -> global cellStart -> scatter.
__global__ __launch_bounds__(256) void build_kernel(const float* __restrict__ pts,
                                                    float4* __restrict__ sorted4,
                                                    int* __restrict__ cellStart,
                                                    float* __restrict__ out) {
    __shared__ int cnt[C_];
    __shared__ int cur[C_];
    __shared__ int lsum[256];
    const int b = blockIdx.x, t = threadIdx.x;
    if (b == 0 && t == 0) out[0] = 0.0f;          // out is poisoned each replay

    for (int c = t; c < C_; c += 256) cnt[c] = 0;
    __syncthreads();

    const float* bp = pts + (size_t)b * N_ * 3;
    int ids[PPT_];
#pragma unroll 4
    for (int q = 0; q < PPT_; q++) {
        const int g = q * 256 + t;
        const float x = bp[g * 3 + 0], y = bp[g * 3 + 1], z = bp[g * 3 + 2];
        const int id = (cell_coord(z) * G_ + cell_coord(y)) * G_ + cell_coord(x);
        ids[q] = id;
        atomicAdd(&cnt[id], 1);
    }
    __syncthreads();

    // exclusive scan of 1728 counters: 7 cells/thread + Hillis-Steele on partials
    int vals[7], tot = 0;
    const int c0 = t * 7;                          // 256*7 = 1792 >= 1728
#pragma unroll
    for (int k = 0; k < 7; k++) {
        const int c = c0 + k;
        const int v = (c < C_) ? cnt[c] : 0;
        vals[k] = v; tot += v;
    }
    lsum[t] = tot;
    __syncthreads();
    for (int off = 1; off < 256; off <<= 1) {
        const int v = (t >= off) ? lsum[t - off] : 0;
        __syncthreads();
        lsum[t] += v;
        __syncthreads();
    }
    int run = lsum[t] - tot;
#pragma unroll
    for (int k = 0; k < 7; k++) {
        const int c = c0 + k;
        if (c < C_) {
            cellStart[b * CS_ + c] = run;
            cur[c] = run;
            run += vals[k];
        }
    }
    if (t == 255) cellStart[b * CS_ + C_] = N_;
    __syncthreads();

#pragma unroll 4
    for (int q = 0; q < PPT_; q++) {
        const int g = q * 256 + t;
        const float x = bp[g * 3 + 0], y = bp[g * 3 + 1], z = bp[g * 3 + 2];
        const int pos = atomicAdd(&cur[ids[q]], 1);
        sorted4[(size_t)b * N_ + pos] = make_float4(x, y, z, 0.0f);
    }
}

// 64 points/block, 4 j-interleaved splits per point.
__global__ __launch_bounds__(256) void query_kernel(const float4* __restrict__ sorted4,
                                                    const int* __restrict__ cellStart,
                                                    float* __restrict__ out) {
    __shared__ int   cs[CS_];              // 6.9 KB
    __shared__ float mergebuf[64 * 32];    // 8 KB
    __shared__ float mbound[64];
    __shared__ float lds_sum;

    const int tid = threadIdx.x;
    const int p   = tid >> 2;              // 0..63 point-in-block
    const int s   = tid & 3;               // 0..3  j-interleave split
    const int blk = blockIdx.x;
    const int b   = blk >> 7;
    const int i   = ((blk & 127) << 6) + p;

    for (int q = tid; q < CS_; q += 256) cs[q] = cellStart[b * CS_ + q];
    if (tid == 0) lds_sum = 0.0f;
    __syncthreads();

    const float4* sp = sorted4 + (size_t)b * N_;
    const float4 P = sp[i];
    const int cx = cell_coord(P.x), cy = cell_coord(P.y), cz = cell_coord(P.z);

    float t[KNN_];
#pragma unroll
    for (int k = 0; k < KNN_; k++) t[k] = 1e30f;

    // Phase A: rings 0+1 = 27 cells, straight-line, j-split by s.
#pragma unroll
    for (int n = 0; n < 27; n++) {
        const int dz = n / 9 - 1, dy = (n / 3) % 3 - 1, dx = n % 3 - 1;
        const int z = cz + dz, y = cy + dy, x = cx + dx;
        if ((unsigned)z >= G_ || (unsigned)y >= G_ || (unsigned)x >= G_) continue;
        const int id = (z * G_ + y) * G_ + x;
        const int j1 = cs[id + 1];
        for (int j = cs[id] + s; j < j1; j += 4) {
            const float4 Q = sp[j];
            const float ddx = P.x - Q.x, ddy = P.y - Q.y, ddz = P.z - Q.z;
            const float d2 = ddx * ddx + ddy * ddy + ddz * ddz;
            if (d2 < t[KNN_ - 1]) insert8(t, d2);
        }
    }

    // Merge the 4 slices -> true 8th-NN bound m (s==0 computes, broadcasts).
#pragma unroll
    for (int k = 0; k < KNN_; k++) mergebuf[tid * 8 + k] = t[k];
    __syncthreads();
    if (s == 0) {
        float mm[KNN_];
#pragma unroll
        for (int k = 0; k < KNN_; k++) mm[k] = t[k];
        for (int v = 8; v < 32; v++) insert8(mm, mergebuf[p * 32 + v]);
        mbound[p] = mm[KNN_ - 1];
    }
    __syncthreads();
    const float m = mbound[p];

    // Exact fallback: scan ring r while ((r-1)*g)^2 < min(m, own t7).
    // Each split keeps only its own j-slice -> final merge stays duplicate-free.
    for (int r = 2; r < G_; r++) {
        const float dmin = (float)(r - 1) * CELL_;
        if (dmin * dmin >= fminf(m, t[KNN_ - 1])) break;
        for (int dz = -r; dz <= r; ++dz)
        for (int dy = -r; dy <= r; ++dy)
        for (int dx = -r; dx <= r; ++dx) {
            const int ch = max(abs(dz), max(abs(dy), abs(dx)));
            if (ch != r) continue;
            const int z = cz + dz, y = cy + dy, x = cx + dx;
            if ((unsigned)z >= G_ || (unsigned)y >= G_ || (unsigned)x >= G_) continue;
            const int id = (z * G_ + y) * G_ + x;
            const int j1 = cs[id + 1];
            for (int j = cs[id] + s; j < j1; j += 4) {
                const float4 Q = sp[j];
                const float ddx = P.x - Q.x, ddy = P.y - Q.y, ddz = P.z - Q.z;
                const float d2 = ddx * ddx + ddy * ddy + ddz * ddz;
                if (d2 < t[KNN_ - 1]) insert8(t, d2);
            }
        }
    }

    // Final merge + loss.
    __syncthreads();   // protect mergebuf reuse
#pragma unroll
    for (int k = 0; k < KNN_; k++) mergebuf[tid * 8 + k] = t[k];
    __syncthreads();
    if (s == 0) {
        for (int v = 8; v < 32; v++) insert8(t, mergebuf[p * 32 + v]);
        float sum = 0.0f;
#pragma unroll
        for (int k = 0; k < KNN_; k++) {
            const float dm = fmaxf(t[k], 1e-12f);   // self: d2=0 -> dn=1e-6
            const float dn = sqrtf(dm);
            sum += (RADIUS_ - dn) * __expf(-dm * INV_H2_);
        }
        atomicAdd(&lds_sum, sum);
    }
    __syncthreads();
    if (tid == 0) atomicAdd(out, lds_sum * SCALE_);
}

extern "C" void kernel_launch(void* const* d_in, const int* in_sizes, int n_in,
                              void* d_out, int out_size, void* d_ws, size_t ws_size,
                              hipStream_t stream) {
    const float* pts = (const float*)d_in[0];
    float*       out = (float*)d_out;

    char* ws = (char*)d_ws;
    float4* sorted4   = (float4*)(ws);               // B*N*16 = 524288 B
    int*    cellStart = (int*)(ws + 524288);         // B*CS*4 =  27664 B

    build_kernel<<<B_,           256, 0, stream>>>(pts, sorted4, cellStart, out);
    query_kernel<<<B_ * N_ / 64, 256, 0, stream>>>(sorted4, cellStart, out);
}